// Round 3
// baseline (160.588 us; speedup 1.0000x reference)
//
#include <hip/hip_runtime.h>
#include <hip/hip_bf16.h>

#define HW 16384
// (1/sqrt(32)) * log2(e): folded into q weights so exp(S) == exp2(S')
#define QSCALE (0.17677669529663687f * 1.4426950408889634f)

typedef __attribute__((ext_vector_type(8))) short short8;
typedef __attribute__((ext_vector_type(4))) float floatx4;

__device__ inline unsigned pack_bf16_2(float a, float b) {
  union { __hip_bfloat162 h; unsigned u; } c;
  c.h = __float22bfloat162_rn(make_float2(a, b));
  return c.u;
}

// ---------------------------------------------------------------------------
// cast_w: w_qkv f32 [384][128] -> bf16, q rows (o<128) pre-scaled by QSCALE
// ---------------------------------------------------------------------------
__global__ __launch_bounds__(256) void cast_w(
    const float* __restrict__ w, unsigned short* __restrict__ w_bf) {
  const int i4 = (blockIdx.x * 256 + threadIdx.x) * 4;  // 48 blocks
  const int o = i4 >> 7;
  const float sc = (o < 128) ? QSCALE : 1.f;
  float4 v = *(const float4*)&w[i4];
  uint2 u = {pack_bf16_2(v.x * sc, v.y * sc), pack_bf16_2(v.z * sc, v.w * sc)};
  *(uint2*)&w_bf[i4] = u;
}

// ---------------------------------------------------------------------------
// cast_transpose_x: x f32 [128][HW] -> x_t bf16 [HW][128]
// grid 256 (p-tiles of 64), block 256
// ---------------------------------------------------------------------------
__global__ __launch_bounds__(256) void cast_transpose_x(
    const float* __restrict__ x, unsigned short* __restrict__ x_t) {
  __shared__ float tile[128][65];
  const int p0 = blockIdx.x * 64;
  const int t = threadIdx.x;
  #pragma unroll
  for (int i = 0; i < 32; ++i) {
    int idx = t + i * 256;
    int c = idx >> 6, p = idx & 63;
    tile[c][p] = x[c * HW + p0 + p];
  }
  __syncthreads();
  const int p = t >> 2, q = t & 3;
  unsigned u[16];
  #pragma unroll
  for (int i = 0; i < 16; ++i)
    u[i] = pack_bf16_2(tile[q * 32 + 2 * i][p], tile[q * 32 + 2 * i + 1][p]);
  unsigned short* dst = &x_t[(p0 + p) * 128 + q * 32];
  #pragma unroll
  for (int i = 0; i < 4; ++i) *(uint4*)&dst[i * 8] = *(const uint4*)&u[i * 4];
}

// ---------------------------------------------------------------------------
// gemm_qkv: MFMA bf16.  A = w_bf[o][c], B = x_t[p][c] (as B^T), K=128.
// q rows -> q_t bf16 [bn][c][32] (QSCALE pre-folded), k rows -> k_t,
// v rows -> v_f f32 [128][HW].
// grid (6 o-tiles of 64, 256 p-tiles of 64), block 256 (4 waves)
// ---------------------------------------------------------------------------
__global__ __launch_bounds__(256) void gemm_qkv(
    const unsigned short* __restrict__ w_bf, const unsigned short* __restrict__ x_t,
    unsigned short* __restrict__ q_t, unsigned short* __restrict__ k_t,
    float* __restrict__ v_f) {
  const int wave = threadIdx.x >> 6, lane = threadIdx.x & 63;
  const int lr = lane & 15, g = lane >> 4;
  const int o0 = blockIdx.x * 64 + wave * 16;
  const int p0 = blockIdx.y * 64;
  const floatx4 zero = {0.f, 0.f, 0.f, 0.f};

  short8 a[4];
  #pragma unroll
  for (int kk = 0; kk < 4; ++kk)
    a[kk] = *(const short8*)&w_bf[(o0 + lr) * 128 + kk * 32 + g * 8];

  floatx4 acc[4] = {zero, zero, zero, zero};
  #pragma unroll
  for (int nf = 0; nf < 4; ++nf) {
    const unsigned short* xr = &x_t[(p0 + nf * 16 + lr) * 128 + g * 8];
    #pragma unroll
    for (int kk = 0; kk < 4; ++kk) {
      short8 b = *(const short8*)&xr[kk * 32];
      acc[nf] = __builtin_amdgcn_mfma_f32_16x16x32_bf16(a[kk], b, acc[nf], 0, 0, 0);
    }
  }

  #pragma unroll
  for (int nf = 0; nf < 4; ++nf) {
    const int p = p0 + nf * 16 + lr;
    const int c = p & 2047, nn = p >> 11;
    if (o0 < 128) {
      const int bh = o0 >> 5, d0 = (o0 & 31) + g * 4;
      uint2 u = {pack_bf16_2(acc[nf][0], acc[nf][1]),
                 pack_bf16_2(acc[nf][2], acc[nf][3])};
      *(uint2*)&q_t[((bh * 8 + nn) * 2048 + c) * 32 + d0] = u;
    } else if (o0 < 256) {
      const int oo = o0 - 128, bh = oo >> 5, d0 = (oo & 31) + g * 4;
      uint2 u = {pack_bf16_2(acc[nf][0], acc[nf][1]),
                 pack_bf16_2(acc[nf][2], acc[nf][3])};
      *(uint2*)&k_t[((bh * 8 + nn) * 2048 + c) * 32 + d0] = u;
    } else {
      const int d = o0 - 256 + g * 4;
      #pragma unroll
      for (int r = 0; r < 4; ++r) v_f[(d + r) * HW + p] = acc[nf][r];
    }
  }
}

// ---------------------------------------------------------------------------
// Pass A: partial Z over e-half.  grid (8 c-tiles, 32 bn, 2 e-halves), block 512
// ---------------------------------------------------------------------------
__global__ __launch_bounds__(512) void attn_stats_mfma(
    const unsigned short* __restrict__ q_t, const unsigned short* __restrict__ k_t,
    float* __restrict__ zpart) {
  const int wave = threadIdx.x >> 6, lane = threadIdx.x & 63;
  const int bn = blockIdx.y, eh = blockIdx.z;
  const int c0 = blockIdx.x * 256 + wave * 32;
  const int lr = lane & 15, g = lane >> 4, lk = g * 8;

  short8 aq0 = *(const short8*)&q_t[(bn * 2048 + c0 + lr) * 32 + lk];
  short8 aq1 = *(const short8*)&q_t[(bn * 2048 + c0 + 16 + lr) * 32 + lk];
  float z[2][4] = {};
  const unsigned short* kb = &k_t[bn * 2048 * 32];
  const floatx4 zero = {0.f, 0.f, 0.f, 0.f};

  for (int e0 = eh * 1024; e0 < eh * 1024 + 1024; e0 += 16) {
    short8 bk = *(const short8*)&kb[(e0 + lr) * 32 + lk];
    floatx4 s0 = __builtin_amdgcn_mfma_f32_16x16x32_bf16(aq0, bk, zero, 0, 0, 0);
    floatx4 s1 = __builtin_amdgcn_mfma_f32_16x16x32_bf16(aq1, bk, zero, 0, 0, 0);
    #pragma unroll
    for (int r = 0; r < 4; ++r) {
      z[0][r] += exp2f(s0[r]);
      z[1][r] += exp2f(s1[r]);
    }
  }
  #pragma unroll
  for (int mt = 0; mt < 2; ++mt) {
    #pragma unroll
    for (int r = 0; r < 4; ++r) {
      float v = z[mt][r];
      v += __shfl_xor(v, 1); v += __shfl_xor(v, 2);
      v += __shfl_xor(v, 4); v += __shfl_xor(v, 8);
      if (lr == 0)
        zpart[eh * 65536 + bn * 2048 + c0 + mt * 16 + g * 4 + r] = v;
    }
  }
}

// ---------------------------------------------------------------------------
// vz = v * 1/(z0+z1), bf16, [d][hw].  grid 2048, block 256
// ---------------------------------------------------------------------------
__global__ __launch_bounds__(256) void vz_cast(
    const float* __restrict__ v_f, const float* __restrict__ zpart,
    unsigned short* __restrict__ vz) {
  const int idx = (blockIdx.x * 256 + threadIdx.x) * 4;
  const int row = idx >> 14, p = idx & 16383;
  const int bh = row >> 5, nn = p >> 11, c = p & 2047;
  float4 v = *(const float4*)&v_f[idx];
  const int zb = (bh * 8 + nn) * 2048 + c;
  float4 z0 = *(const float4*)&zpart[zb];
  float4 z1 = *(const float4*)&zpart[65536 + zb];
  unsigned u0 = pack_bf16_2(v.x / (z0.x + z1.x), v.y / (z0.y + z1.y));
  unsigned u1 = pack_bf16_2(v.z / (z0.z + z1.z), v.w / (z0.w + z1.w));
  uint2 o = {u0, u1};
  *(uint2*)&vz[idx] = o;
}

// ---------------------------------------------------------------------------
// Pass B: partial PV over c-half.  grid (8 j-tiles, 32 bn, 2 c-halves), block 512
// Per-wave private P^T tile (padded to 40 shorts -> conflict-free)
// ---------------------------------------------------------------------------
__global__ __launch_bounds__(512) void attn_apply_mfma(
    const unsigned short* __restrict__ q_t, const unsigned short* __restrict__ k_t,
    const unsigned short* __restrict__ vz, float* __restrict__ attn_part) {
  __shared__ unsigned short pt[8][32][40];
  const int wave = threadIdx.x >> 6, lane = threadIdx.x & 63;
  const int bn = blockIdx.y, bh = bn >> 3, nn = bn & 7;
  const int j0 = blockIdx.x * 256 + wave * 32;
  const int chf = blockIdx.z;
  const int lr = lane & 15, g = lane >> 4, lk = g * 8;
  const floatx4 zero = {0.f, 0.f, 0.f, 0.f};

  short8 bk0 = *(const short8*)&k_t[(bn * 2048 + j0 + lr) * 32 + lk];
  short8 bk1 = *(const short8*)&k_t[(bn * 2048 + j0 + 16 + lr) * 32 + lk];

  floatx4 acc[2][2] = {{zero, zero}, {zero, zero}};
  const int pcol = g * 4;

  for (int c0 = chf * 1024; c0 < chf * 1024 + 1024; c0 += 32) {
    short8 aq0 = *(const short8*)&q_t[(bn * 2048 + c0 + lr) * 32 + lk];
    short8 aq1 = *(const short8*)&q_t[(bn * 2048 + c0 + 16 + lr) * 32 + lk];
    floatx4 s00 = __builtin_amdgcn_mfma_f32_16x16x32_bf16(aq0, bk0, zero, 0, 0, 0);
    floatx4 s01 = __builtin_amdgcn_mfma_f32_16x16x32_bf16(aq0, bk1, zero, 0, 0, 0);
    floatx4 s10 = __builtin_amdgcn_mfma_f32_16x16x32_bf16(aq1, bk0, zero, 0, 0, 0);
    floatx4 s11 = __builtin_amdgcn_mfma_f32_16x16x32_bf16(aq1, bk1, zero, 0, 0, 0);

    {
      uint2 w00 = {pack_bf16_2(exp2f(s00[0]), exp2f(s00[1])),
                   pack_bf16_2(exp2f(s00[2]), exp2f(s00[3]))};
      *(uint2*)&pt[wave][lr][pcol] = w00;
      uint2 w01 = {pack_bf16_2(exp2f(s01[0]), exp2f(s01[1])),
                   pack_bf16_2(exp2f(s01[2]), exp2f(s01[3]))};
      *(uint2*)&pt[wave][16 + lr][pcol] = w01;
      uint2 w10 = {pack_bf16_2(exp2f(s10[0]), exp2f(s10[1])),
                   pack_bf16_2(exp2f(s10[2]), exp2f(s10[3]))};
      *(uint2*)&pt[wave][lr][16 + pcol] = w10;
      uint2 w11 = {pack_bf16_2(exp2f(s11[0]), exp2f(s11[1])),
                   pack_bf16_2(exp2f(s11[2]), exp2f(s11[3]))};
      *(uint2*)&pt[wave][16 + lr][16 + pcol] = w11;
    }

    short8 av0 = *(const short8*)&vz[(bh * 32 + lr) * HW + nn * 2048 + c0 + lk];
    short8 av1 = *(const short8*)&vz[(bh * 32 + 16 + lr) * HW + nn * 2048 + c0 + lk];
    short8 bp0 = *(const short8*)&pt[wave][lr][lk];
    short8 bp1 = *(const short8*)&pt[wave][16 + lr][lk];

    acc[0][0] = __builtin_amdgcn_mfma_f32_16x16x32_bf16(av0, bp0, acc[0][0], 0, 0, 0);
    acc[0][1] = __builtin_amdgcn_mfma_f32_16x16x32_bf16(av0, bp1, acc[0][1], 0, 0, 0);
    acc[1][0] = __builtin_amdgcn_mfma_f32_16x16x32_bf16(av1, bp0, acc[1][0], 0, 0, 0);
    acc[1][1] = __builtin_amdgcn_mfma_f32_16x16x32_bf16(av1, bp1, acc[1][1], 0, 0, 0);
  }

  float* outp = attn_part + chf * 2097152;
  #pragma unroll
  for (int m = 0; m < 2; ++m)
    #pragma unroll
    for (int nt = 0; nt < 2; ++nt)
      #pragma unroll
      for (int r = 0; r < 4; ++r)
        outp[(bh * 32 + m * 16 + g * 4 + r) * HW +
             nn * 2048 + j0 + nt * 16 + lr] = acc[m][nt][r];
}

// ---------------------------------------------------------------------------
// K4a: per-channel mean of (part0+part1) -> s[128]
// ---------------------------------------------------------------------------
__global__ __launch_bounds__(256) void row_mean(
    const float* __restrict__ part, float* __restrict__ s) {
  const int ch = blockIdx.x;
  float sum = 0;
  const float4* r0 = (const float4*)(part + ch * HW);
  const float4* r1 = (const float4*)(part + 2097152 + ch * HW);
  for (int p = threadIdx.x; p < HW / 4; p += 256) {
    float4 a = r0[p], b = r1[p];
    sum += (a.x + a.y) + (a.z + a.w) + (b.x + b.y) + (b.z + b.w);
  }
  __shared__ float red[256];
  red[threadIdx.x] = sum;
  __syncthreads();
  for (int st = 128; st > 0; st >>= 1) {
    if (threadIdx.x < st) red[threadIdx.x] += red[threadIdx.x + st];
    __syncthreads();
  }
  if (threadIdx.x == 0) s[ch] = red[0] * (1.f / HW);
}

// ---------------------------------------------------------------------------
// K4b: SE MLP -> gate folded into out_w -> w_g
// ---------------------------------------------------------------------------
__global__ __launch_bounds__(128) void se_mlp(
    const float* __restrict__ s, const float* __restrict__ w1,
    const float* __restrict__ b1, const float* __restrict__ w2,
    const float* __restrict__ b2, const float* __restrict__ out_w,
    float* __restrict__ w_g) {
  __shared__ float s_sh[128], s1_sh[32], g_sh[128];
  const int t = threadIdx.x;
  s_sh[t] = s[t];
  __syncthreads();
  if (t < 32) {
    float a = b1[t];
    for (int c = 0; c < 128; ++c) a += w1[t * 128 + c] * s_sh[c];
    s1_sh[t] = a / (1.f + __expf(-a));
  }
  __syncthreads();
  {
    float a = b2[t];
    for (int i = 0; i < 32; ++i) a += w2[t * 32 + i] * s1_sh[i];
    g_sh[t] = 1.f / (1.f + __expf(-a));
  }
  __syncthreads();
  for (int o = 0; o < 128; ++o) w_g[o * 128 + t] = out_w[o * 128 + t] * g_sh[t];
}

// ---------------------------------------------------------------------------
// K5: Y[o][p] = sum_c W[o][c] * (X0[c][p]+X1[c][p]) + bias[o]   fp32
// grid (M/64, HW/128), block 256
// ---------------------------------------------------------------------------
__global__ __launch_bounds__(256) void gemm_ox_sum(
    const float* __restrict__ W, const float* __restrict__ X0,
    const float* __restrict__ X1, const float* __restrict__ bias,
    float* __restrict__ Y) {
  __shared__ float w_s[64][128];
  __shared__ float x_s[16][128];
  const int o0 = blockIdx.x * 64;
  const int p0 = blockIdx.y * 128;
  const int t = threadIdx.x;

  #pragma unroll
  for (int i = 0; i < 32; ++i) {
    int idx = t + i * 256;
    int o = idx >> 7, c = idx & 127;
    w_s[o][c] = W[(o0 + o) * 128 + c];
  }

  float acc[8][4] = {};
  const int pt = t & 31, ot = t >> 5;

  for (int c0 = 0; c0 < 128; c0 += 16) {
    __syncthreads();
    #pragma unroll
    for (int i = 0; i < 8; ++i) {
      int idx = t + i * 256;
      int cc = idx >> 7, p = idx & 127;
      x_s[cc][p] = X0[(c0 + cc) * HW + p0 + p] + X1[(c0 + cc) * HW + p0 + p];
    }
    __syncthreads();
    #pragma unroll
    for (int cc = 0; cc < 16; ++cc) {
      float4 xv = *(const float4*)&x_s[cc][pt * 4];
      #pragma unroll
      for (int oo = 0; oo < 8; ++oo) {
        float wv = w_s[ot * 8 + oo][c0 + cc];
        acc[oo][0] += wv * xv.x; acc[oo][1] += wv * xv.y;
        acc[oo][2] += wv * xv.z; acc[oo][3] += wv * xv.w;
      }
    }
  }
  #pragma unroll
  for (int oo = 0; oo < 8; ++oo) {
    int o = o0 + ot * 8 + oo;
    float b = bias[o];
    float4 r = {acc[oo][0] + b, acc[oo][1] + b, acc[oo][2] + b, acc[oo][3] + b};
    *(float4*)&Y[o * HW + p0 + pt * 4] = r;
  }
}

// ---------------------------------------------------------------------------
// GroupNorm
// ---------------------------------------------------------------------------
__global__ __launch_bounds__(256) void gn_partial(
    const float* __restrict__ y, float* __restrict__ part) {
  const int g = blockIdx.x, bk = blockIdx.y;
  float s = 0, ss = 0;
  const float4* base = (const float4*)(y + g * 16 * HW + bk * 8192);
  for (int i = threadIdx.x; i < 2048; i += 256) {
    float4 v = base[i];
    s += (v.x + v.y) + (v.z + v.w);
    ss += (v.x * v.x + v.y * v.y) + (v.z * v.z + v.w * v.w);
  }
  __shared__ float r1[256], r2[256];
  r1[threadIdx.x] = s; r2[threadIdx.x] = ss;
  __syncthreads();
  for (int st = 128; st > 0; st >>= 1) {
    if (threadIdx.x < st) {
      r1[threadIdx.x] += r1[threadIdx.x + st];
      r2[threadIdx.x] += r2[threadIdx.x + st];
    }
    __syncthreads();
  }
  if (threadIdx.x == 0) {
    part[(g * 32 + bk) * 2 + 0] = r1[0];
    part[(g * 32 + bk) * 2 + 1] = r2[0];
  }
}

__global__ void gn_finalize(const float* __restrict__ part, float* __restrict__ stat) {
  const int g = threadIdx.x;
  if (g >= 8) return;
  float s = 0, ss = 0;
  for (int i = 0; i < 32; ++i) {
    s += part[(g * 32 + i) * 2 + 0];
    ss += part[(g * 32 + i) * 2 + 1];
  }
  const float inv_n = 1.f / (16.f * HW);
  float mu = s * inv_n;
  float var = ss * inv_n - mu * mu;
  stat[g * 2 + 0] = mu;
  stat[g * 2 + 1] = rsqrtf(var + 1e-5f);
}

__global__ __launch_bounds__(256) void gn_apply(
    const float* __restrict__ y, const float* __restrict__ stat,
    const float* __restrict__ gn_w, const float* __restrict__ gn_b,
    float* __restrict__ outp) {
  const int i = (blockIdx.x * 256 + threadIdx.x) * 4;
  const int ch = i >> 14;
  const int g = ch >> 4;
  float mu = stat[g * 2], rs = stat[g * 2 + 1];
  float w = gn_w[ch] * rs;
  float b = gn_b[ch] - mu * w;
  float4 v = *(const float4*)&y[i];
  float4 r = {v.x * w + b, v.y * w + b, v.z * w + b, v.w * w + b};
  *(float4*)&outp[i] = r;
}

// ---------------------------------------------------------------------------
extern "C" void kernel_launch(void* const* d_in, const int* in_sizes, int n_in,
                              void* d_out, int out_size, void* d_ws, size_t ws_size,
                              hipStream_t stream) {
  const float* x     = (const float*)d_in[0];
  const float* w_qkv = (const float*)d_in[1];
  const float* se_w1 = (const float*)d_in[2];
  const float* se_b1 = (const float*)d_in[3];
  const float* se_w2 = (const float*)d_in[4];
  const float* se_b2 = (const float*)d_in[5];
  const float* out_w = (const float*)d_in[6];
  const float* out_b = (const float*)d_in[7];
  const float* gn_w  = (const float*)d_in[8];
  const float* gn_b  = (const float*)d_in[9];
  float* out = (float*)d_out;

  float* ws = (float*)d_ws;
  float* v_f       = ws;                        // 2097152 f
  float* zpart     = v_f + 2097152;             // 2*65536 f
  float* attn_part = zpart + 131072;            // 2*2097152 f
  float* se_s      = attn_part + 4194304;       // 128 f
  float* w_g       = se_s + 128;                // 16384 f
  float* ybuf      = w_g + 16384;               // 2097152 f
  float* part      = ybuf + 2097152;            // 512 f
  float* stat      = part + 512;                // 16 f
  unsigned short* w_bf = (unsigned short*)(stat + 16);  // 49152 sh
  unsigned short* x_t  = w_bf + 49152;                  // 2097152 sh
  unsigned short* q_t  = x_t + 2097152;                 // 2097152 sh
  unsigned short* k_t  = q_t + 2097152;                 // 2097152 sh
  unsigned short* vz   = k_t + 2097152;                 // 2097152 sh

  cast_w<<<48, 256, 0, stream>>>(w_qkv, w_bf);
  cast_transpose_x<<<256, 256, 0, stream>>>(x, x_t);
  gemm_qkv<<<dim3(6, 256), 256, 0, stream>>>(w_bf, x_t, q_t, k_t, v_f);
  attn_stats_mfma<<<dim3(8, 32, 2), 512, 0, stream>>>(q_t, k_t, zpart);
  vz_cast<<<2048, 256, 0, stream>>>(v_f, zpart, vz);
  attn_apply_mfma<<<dim3(8, 32, 2), 512, 0, stream>>>(q_t, k_t, vz, attn_part);
  row_mean<<<128, 256, 0, stream>>>(attn_part, se_s);
  se_mlp<<<1, 128, 0, stream>>>(se_s, se_w1, se_b1, se_w2, se_b2, out_w, w_g);
  gemm_ox_sum<<<dim3(2, 128), 256, 0, stream>>>(w_g, attn_part, attn_part + 2097152,
                                                out_b, ybuf);
  gn_partial<<<dim3(8, 32), 256, 0, stream>>>(ybuf, part);
  gn_finalize<<<1, 64, 0, stream>>>(part, stat);
  gn_apply<<<2048, 256, 0, stream>>>(ybuf, stat, gn_w, gn_b, out);
}

// Round 4
// 138.482 us; speedup vs baseline: 1.1596x; 1.1596x over previous
//
#include <hip/hip_runtime.h>
#include <hip/hip_bf16.h>

#define HW 16384
// (1/sqrt(32)) * log2(e): folded into q weights so exp(S) == exp2(S')
#define QSCALE (0.17677669529663687f * 1.4426950408889634f)

typedef __attribute__((ext_vector_type(8))) short short8;
typedef __attribute__((ext_vector_type(4))) float floatx4;

__device__ inline unsigned pack_bf16_2(float a, float b) {
  union { __hip_bfloat162 h; unsigned u; } c;
  c.h = __float22bfloat162_rn(make_float2(a, b));
  return c.u;
}

// HW packed convert: lo = bf16(a), hi = bf16(b)  (RNE on gfx950)
__device__ inline unsigned cvt_pk_bf16(float a, float b) {
  unsigned r;
  asm("v_cvt_pk_bf16_f32 %0, %1, %2" : "=v"(r) : "v"(a), "v"(b));
  return r;
}

__device__ inline float bf2f(unsigned short u) {
  union { unsigned u; float f; } c;
  c.u = (unsigned)u << 16;
  return c.f;
}

// ---------------------------------------------------------------------------
// cast_w: w_qkv f32 [384][128] -> bf16, q rows (o<128) pre-scaled by QSCALE
// ---------------------------------------------------------------------------
__global__ __launch_bounds__(256) void cast_w(
    const float* __restrict__ w, unsigned short* __restrict__ w_bf) {
  const int i4 = (blockIdx.x * 256 + threadIdx.x) * 4;  // 48 blocks
  const int o = i4 >> 7;
  const float sc = (o < 128) ? QSCALE : 1.f;
  float4 v = *(const float4*)&w[i4];
  uint2 u = {pack_bf16_2(v.x * sc, v.y * sc), pack_bf16_2(v.z * sc, v.w * sc)};
  *(uint2*)&w_bf[i4] = u;
}

// ---------------------------------------------------------------------------
// cast_transpose_x: x f32 [128][HW] -> x_t bf16 [HW][128]
// ---------------------------------------------------------------------------
__global__ __launch_bounds__(256) void cast_transpose_x(
    const float* __restrict__ x, unsigned short* __restrict__ x_t) {
  __shared__ float tile[128][65];
  const int p0 = blockIdx.x * 64;
  const int t = threadIdx.x;
  #pragma unroll
  for (int i = 0; i < 32; ++i) {
    int idx = t + i * 256;
    int c = idx >> 6, p = idx & 63;
    tile[c][p] = x[c * HW + p0 + p];
  }
  __syncthreads();
  const int p = t >> 2, q = t & 3;
  unsigned u[16];
  #pragma unroll
  for (int i = 0; i < 16; ++i)
    u[i] = pack_bf16_2(tile[q * 32 + 2 * i][p], tile[q * 32 + 2 * i + 1][p]);
  unsigned short* dst = &x_t[(p0 + p) * 128 + q * 32];
  #pragma unroll
  for (int i = 0; i < 4; ++i) *(uint4*)&dst[i * 8] = *(const uint4*)&u[i * 4];
}

// ---------------------------------------------------------------------------
// gemm_qkv: MFMA bf16, one block computes ALL 384 o-rows for a 64-p slab.
// q -> q_t bf16 [bn][c][32], k -> k_t, v -> v_bf bf16 [128][HW].
// grid 256 p-tiles, block 512 (8 waves x 48 o-rows)
// ---------------------------------------------------------------------------
__global__ __launch_bounds__(512) void gemm_qkv(
    const unsigned short* __restrict__ w_bf, const unsigned short* __restrict__ x_t,
    unsigned short* __restrict__ q_t, unsigned short* __restrict__ k_t,
    unsigned short* __restrict__ v_bf) {
  const int wave = threadIdx.x >> 6, lane = threadIdx.x & 63;
  const int lr = lane & 15, g = lane >> 4;
  const int p0 = blockIdx.x * 64;
  const int ow = wave * 48;
  const floatx4 zero = {0.f, 0.f, 0.f, 0.f};

  short8 a[3][4];
  #pragma unroll
  for (int mf = 0; mf < 3; ++mf)
    #pragma unroll
    for (int kk = 0; kk < 4; ++kk)
      a[mf][kk] = *(const short8*)&w_bf[(ow + mf * 16 + lr) * 128 + kk * 32 + g * 8];

  floatx4 acc[3][4];
  #pragma unroll
  for (int mf = 0; mf < 3; ++mf)
    #pragma unroll
    for (int nf = 0; nf < 4; ++nf) acc[mf][nf] = zero;

  #pragma unroll
  for (int kk = 0; kk < 4; ++kk) {
    #pragma unroll
    for (int nf = 0; nf < 4; ++nf) {
      short8 b = *(const short8*)&x_t[(p0 + nf * 16 + lr) * 128 + kk * 32 + g * 8];
      #pragma unroll
      for (int mf = 0; mf < 3; ++mf)
        acc[mf][nf] = __builtin_amdgcn_mfma_f32_16x16x32_bf16(a[mf][kk], b, acc[mf][nf], 0, 0, 0);
    }
  }

  #pragma unroll
  for (int mf = 0; mf < 3; ++mf) {
    const int ob = ow + mf * 16;
    #pragma unroll
    for (int nf = 0; nf < 4; ++nf) {
      const int p = p0 + nf * 16 + lr;
      const int c = p & 2047, nn = p >> 11;
      floatx4 r = acc[mf][nf];
      if (ob < 128) {
        const int bh = ob >> 5, d0 = (ob & 31) + g * 4;
        uint2 u = {cvt_pk_bf16(r[0], r[1]), cvt_pk_bf16(r[2], r[3])};
        *(uint2*)&q_t[((bh * 8 + nn) * 2048 + c) * 32 + d0] = u;
      } else if (ob < 256) {
        const int oo = ob - 128, bh = oo >> 5, d0 = (oo & 31) + g * 4;
        uint2 u = {cvt_pk_bf16(r[0], r[1]), cvt_pk_bf16(r[2], r[3])};
        *(uint2*)&k_t[((bh * 8 + nn) * 2048 + c) * 32 + d0] = u;
      } else {
        const int d = ob - 256 + g * 4;
        unsigned u01 = cvt_pk_bf16(r[0], r[1]);
        unsigned u23 = cvt_pk_bf16(r[2], r[3]);
        v_bf[(d + 0) * HW + p] = (unsigned short)(u01 & 0xffff);
        v_bf[(d + 1) * HW + p] = (unsigned short)(u01 >> 16);
        v_bf[(d + 2) * HW + p] = (unsigned short)(u23 & 0xffff);
        v_bf[(d + 3) * HW + p] = (unsigned short)(u23 >> 16);
      }
    }
  }
}

// ---------------------------------------------------------------------------
// row_mean_v: s[ch] = mean of v row (softmax rows sum to 1 => SE input)
// ---------------------------------------------------------------------------
__global__ __launch_bounds__(256) void row_mean_v(
    const unsigned short* __restrict__ v_bf, float* __restrict__ s) {
  const int ch = blockIdx.x;
  float sum = 0;
  for (int i = threadIdx.x; i < 2048; i += 256) {
    short8 u = *(const short8*)&v_bf[ch * HW + i * 8];
    #pragma unroll
    for (int k = 0; k < 8; ++k) sum += bf2f((unsigned short)u[k]);
  }
  __shared__ float red[256];
  red[threadIdx.x] = sum;
  __syncthreads();
  for (int st = 128; st > 0; st >>= 1) {
    if (threadIdx.x < st) red[threadIdx.x] += red[threadIdx.x + st];
    __syncthreads();
  }
  if (threadIdx.x == 0) s[ch] = red[0] * (1.f / HW);
}

// ---------------------------------------------------------------------------
// se_mlp: gate g from mean(v); writes w_g = out_w * g  as BF16
// ---------------------------------------------------------------------------
__global__ __launch_bounds__(128) void se_mlp(
    const float* __restrict__ s, const float* __restrict__ w1,
    const float* __restrict__ b1, const float* __restrict__ w2,
    const float* __restrict__ b2, const float* __restrict__ out_w,
    unsigned short* __restrict__ w_g) {
  __shared__ float s_sh[128], s1_sh[32], g_sh[128];
  const int t = threadIdx.x;
  s_sh[t] = s[t];
  __syncthreads();
  if (t < 32) {
    float a = b1[t];
    for (int c = 0; c < 128; ++c) a += w1[t * 128 + c] * s_sh[c];
    s1_sh[t] = a / (1.f + __expf(-a));
  }
  __syncthreads();
  {
    float a = b2[t];
    for (int i = 0; i < 32; ++i) a += w2[t * 32 + i] * s1_sh[i];
    g_sh[t] = 1.f / (1.f + __expf(-a));
  }
  __syncthreads();
  for (int o = 0; o < 128; ++o)
    w_g[o * 128 + t] = (unsigned short)(cvt_pk_bf16(out_w[o * 128 + t] * g_sh[t], 0.f) & 0xffff);
}

// ---------------------------------------------------------------------------
// Pass A: partial Z over e-half.  grid (8 c-tiles, 32 bn, 2 eh), block 512
// ---------------------------------------------------------------------------
__global__ __launch_bounds__(512) void attn_stats_mfma(
    const unsigned short* __restrict__ q_t, const unsigned short* __restrict__ k_t,
    float* __restrict__ zpart) {
  const int wave = threadIdx.x >> 6, lane = threadIdx.x & 63;
  const int bn = blockIdx.y, eh = blockIdx.z;
  const int c0 = blockIdx.x * 256 + wave * 32;
  const int lr = lane & 15, g = lane >> 4, lk = g * 8;

  short8 aq0 = *(const short8*)&q_t[(bn * 2048 + c0 + lr) * 32 + lk];
  short8 aq1 = *(const short8*)&q_t[(bn * 2048 + c0 + 16 + lr) * 32 + lk];
  float z[2][4] = {};
  const unsigned short* kb = &k_t[(bn * 2048 + eh * 1024) * 32];
  const floatx4 zero = {0.f, 0.f, 0.f, 0.f};

  for (int e0 = 0; e0 < 1024; e0 += 16) {
    short8 bk = *(const short8*)&kb[(e0 + lr) * 32 + lk];
    floatx4 s0 = __builtin_amdgcn_mfma_f32_16x16x32_bf16(aq0, bk, zero, 0, 0, 0);
    floatx4 s1 = __builtin_amdgcn_mfma_f32_16x16x32_bf16(aq1, bk, zero, 0, 0, 0);
    #pragma unroll
    for (int r = 0; r < 4; ++r) {
      z[0][r] += exp2f(s0[r]);
      z[1][r] += exp2f(s1[r]);
    }
  }
  #pragma unroll
  for (int mt = 0; mt < 2; ++mt) {
    #pragma unroll
    for (int r = 0; r < 4; ++r) {
      float v = z[mt][r];
      v += __shfl_xor(v, 1); v += __shfl_xor(v, 2);
      v += __shfl_xor(v, 4); v += __shfl_xor(v, 8);
      if (lr == 0)
        zpart[eh * 65536 + bn * 2048 + c0 + mt * 16 + g * 4 + r] = v;
    }
  }
}

// ---------------------------------------------------------------------------
// vz = v / (z0+z1), bf16 [d][hw].  grid 1024, block 256, 8 elts/thread
// ---------------------------------------------------------------------------
__global__ __launch_bounds__(256) void vz_cast(
    const unsigned short* __restrict__ v_bf, const float* __restrict__ zpart,
    unsigned short* __restrict__ vz) {
  const int idx = (blockIdx.x * 256 + threadIdx.x) * 8;
  const int row = idx >> 14, p = idx & 16383;
  const int bh = row >> 5, nn = p >> 11, c = p & 2047;
  short8 v8 = *(const short8*)&v_bf[idx];
  const int zb = (bh * 8 + nn) * 2048 + c;
  float4 z0a = *(const float4*)&zpart[zb];
  float4 z0b = *(const float4*)&zpart[zb + 4];
  float4 z1a = *(const float4*)&zpart[65536 + zb];
  float4 z1b = *(const float4*)&zpart[65536 + zb + 4];
  float zr[8] = {
    __builtin_amdgcn_rcpf(z0a.x + z1a.x), __builtin_amdgcn_rcpf(z0a.y + z1a.y),
    __builtin_amdgcn_rcpf(z0a.z + z1a.z), __builtin_amdgcn_rcpf(z0a.w + z1a.w),
    __builtin_amdgcn_rcpf(z0b.x + z1b.x), __builtin_amdgcn_rcpf(z0b.y + z1b.y),
    __builtin_amdgcn_rcpf(z0b.z + z1b.z), __builtin_amdgcn_rcpf(z0b.w + z1b.w)};
  unsigned u[4];
  #pragma unroll
  for (int i = 0; i < 4; ++i)
    u[i] = cvt_pk_bf16(bf2f((unsigned short)v8[2 * i]) * zr[2 * i],
                       bf2f((unsigned short)v8[2 * i + 1]) * zr[2 * i + 1]);
  uint4 o = {u[0], u[1], u[2], u[3]};
  *(uint4*)&vz[idx] = o;
}

// ---------------------------------------------------------------------------
// Pass B: partial PV over c-half -> att_t bf16 TRANSPOSED [hw][128].
// grid (8 j-tiles, 32 bn, 2 chf), block 512.
// ---------------------------------------------------------------------------
__global__ __launch_bounds__(512) void attn_apply_mfma(
    const unsigned short* __restrict__ q_t, const unsigned short* __restrict__ k_t,
    const unsigned short* __restrict__ vz, unsigned short* __restrict__ att_t) {
  __shared__ unsigned short pt[8][32][40];
  const int wave = threadIdx.x >> 6, lane = threadIdx.x & 63;
  const int bn = blockIdx.y, bh = bn >> 3, nn = bn & 7;
  const int j0 = blockIdx.x * 256 + wave * 32;
  const int chf = blockIdx.z;
  const int lr = lane & 15, g = lane >> 4, lk = g * 8;
  const floatx4 zero = {0.f, 0.f, 0.f, 0.f};

  short8 bk0 = *(const short8*)&k_t[(bn * 2048 + j0 + lr) * 32 + lk];
  short8 bk1 = *(const short8*)&k_t[(bn * 2048 + j0 + 16 + lr) * 32 + lk];

  floatx4 acc[2][2] = {{zero, zero}, {zero, zero}};
  const int pcol = g * 4;
  const unsigned short* qb = &q_t[(bn * 2048 + chf * 1024) * 32];
  const unsigned short* vb = &vz[nn * 2048 + chf * 1024];

  for (int c0 = 0; c0 < 1024; c0 += 32) {
    short8 aq0 = *(const short8*)&qb[(c0 + lr) * 32 + lk];
    short8 aq1 = *(const short8*)&qb[(c0 + 16 + lr) * 32 + lk];
    floatx4 s00 = __builtin_amdgcn_mfma_f32_16x16x32_bf16(aq0, bk0, zero, 0, 0, 0);
    floatx4 s01 = __builtin_amdgcn_mfma_f32_16x16x32_bf16(aq0, bk1, zero, 0, 0, 0);
    floatx4 s10 = __builtin_amdgcn_mfma_f32_16x16x32_bf16(aq1, bk0, zero, 0, 0, 0);
    floatx4 s11 = __builtin_amdgcn_mfma_f32_16x16x32_bf16(aq1, bk1, zero, 0, 0, 0);

    float e00a = exp2f(s00[0]), e00b = exp2f(s00[1]), e00c = exp2f(s00[2]), e00d = exp2f(s00[3]);
    float e01a = exp2f(s01[0]), e01b = exp2f(s01[1]), e01c = exp2f(s01[2]), e01d = exp2f(s01[3]);
    float e10a = exp2f(s10[0]), e10b = exp2f(s10[1]), e10c = exp2f(s10[2]), e10d = exp2f(s10[3]);
    float e11a = exp2f(s11[0]), e11b = exp2f(s11[1]), e11c = exp2f(s11[2]), e11d = exp2f(s11[3]);

    uint2 w00 = {cvt_pk_bf16(e00a, e00b), cvt_pk_bf16(e00c, e00d)};
    *(uint2*)&pt[wave][lr][pcol] = w00;
    uint2 w01 = {cvt_pk_bf16(e01a, e01b), cvt_pk_bf16(e01c, e01d)};
    *(uint2*)&pt[wave][16 + lr][pcol] = w01;
    uint2 w10 = {cvt_pk_bf16(e10a, e10b), cvt_pk_bf16(e10c, e10d)};
    *(uint2*)&pt[wave][lr][16 + pcol] = w10;
    uint2 w11 = {cvt_pk_bf16(e11a, e11b), cvt_pk_bf16(e11c, e11d)};
    *(uint2*)&pt[wave][16 + lr][16 + pcol] = w11;

    short8 av0 = *(const short8*)&vb[(bh * 32 + lr) * HW + c0 + lk];
    short8 av1 = *(const short8*)&vb[(bh * 32 + 16 + lr) * HW + c0 + lk];
    short8 bp0 = *(const short8*)&pt[wave][lr][lk];
    short8 bp1 = *(const short8*)&pt[wave][16 + lr][lk];

    acc[0][0] = __builtin_amdgcn_mfma_f32_16x16x32_bf16(av0, bp0, acc[0][0], 0, 0, 0);
    acc[0][1] = __builtin_amdgcn_mfma_f32_16x16x32_bf16(av0, bp1, acc[0][1], 0, 0, 0);
    acc[1][0] = __builtin_amdgcn_mfma_f32_16x16x32_bf16(av1, bp0, acc[1][0], 0, 0, 0);
    acc[1][1] = __builtin_amdgcn_mfma_f32_16x16x32_bf16(av1, bp1, acc[1][1], 0, 0, 0);
  }

  unsigned short* outp = att_t + chf * 2097152;
  #pragma unroll
  for (int m = 0; m < 2; ++m)
    #pragma unroll
    for (int nt = 0; nt < 2; ++nt) {
      uint2 u = {cvt_pk_bf16(acc[m][nt][0], acc[m][nt][1]),
                 cvt_pk_bf16(acc[m][nt][2], acc[m][nt][3])};
      *(uint2*)&outp[(nn * 2048 + j0 + nt * 16 + lr) * 128 + bh * 32 + m * 16 + g * 4] = u;
    }
}

// ---------------------------------------------------------------------------
// gemm_out: y = w_g @ (att0+att1) + out_b, MFMA K=256 (halves concat on K);
// epilogue stores ybuf f32 and per-block GroupNorm partials.
// grid 256 p-tiles of 64, block 256 (4 waves x 32 o-rows)
// ---------------------------------------------------------------------------
__global__ __launch_bounds__(256) void gemm_out(
    const unsigned short* __restrict__ w_g, const unsigned short* __restrict__ att_t,
    const float* __restrict__ out_b, float* __restrict__ ybuf,
    float* __restrict__ part) {
  const int wave = threadIdx.x >> 6, lane = threadIdx.x & 63;
  const int lr = lane & 15, g = lane >> 4;
  const int p0 = blockIdx.x * 64;
  const int o0 = wave * 32;
  const floatx4 zero = {0.f, 0.f, 0.f, 0.f};

  short8 a[2][4];
  #pragma unroll
  for (int mf = 0; mf < 2; ++mf)
    #pragma unroll
    for (int kk = 0; kk < 4; ++kk)
      a[mf][kk] = *(const short8*)&w_g[(o0 + mf * 16 + lr) * 128 + kk * 32 + g * 8];

  floatx4 acc[2][4];
  #pragma unroll
  for (int mf = 0; mf < 2; ++mf)
    #pragma unroll
    for (int nf = 0; nf < 4; ++nf) acc[mf][nf] = zero;

  #pragma unroll
  for (int ks = 0; ks < 8; ++ks) {
    const unsigned short* att = att_t + (ks >> 2) * 2097152;
    const int kk = ks & 3;
    #pragma unroll
    for (int nf = 0; nf < 4; ++nf) {
      short8 b = *(const short8*)&att[(p0 + nf * 16 + lr) * 128 + kk * 32 + g * 8];
      acc[0][nf] = __builtin_amdgcn_mfma_f32_16x16x32_bf16(a[0][kk], b, acc[0][nf], 0, 0, 0);
      acc[1][nf] = __builtin_amdgcn_mfma_f32_16x16x32_bf16(a[1][kk], b, acc[1][nf], 0, 0, 0);
    }
  }

  float sg[2] = {0.f, 0.f}, ssg[2] = {0.f, 0.f};
  #pragma unroll
  for (int mf = 0; mf < 2; ++mf) {
    #pragma unroll
    for (int nf = 0; nf < 4; ++nf) {
      #pragma unroll
      for (int r = 0; r < 4; ++r) {
        const int o = o0 + mf * 16 + g * 4 + r;
        float y = acc[mf][nf][r] + out_b[o];
        ybuf[o * HW + p0 + nf * 16 + lr] = y;
        sg[mf] += y;
        ssg[mf] += y * y;
      }
    }
  }
  // all 64 lanes of (wave, mf) belong to one GN group = wave*2+mf
  #pragma unroll
  for (int mf = 0; mf < 2; ++mf) {
    float a1 = sg[mf], a2 = ssg[mf];
    #pragma unroll
    for (int st = 1; st < 64; st <<= 1) {
      a1 += __shfl_xor(a1, st);
      a2 += __shfl_xor(a2, st);
    }
    if (lane == 0) {
      part[(blockIdx.x * 8 + wave * 2 + mf) * 2 + 0] = a1;
      part[(blockIdx.x * 8 + wave * 2 + mf) * 2 + 1] = a2;
    }
  }
}

// ---------------------------------------------------------------------------
// gn_finalize: reduce 256 p-block partials per group. grid 8, block 256
// ---------------------------------------------------------------------------
__global__ __launch_bounds__(256) void gn_finalize(
    const float* __restrict__ part, float* __restrict__ stat) {
  const int gg = blockIdx.x;
  const int t = threadIdx.x;
  __shared__ float r1[256], r2[256];
  r1[t] = part[(t * 8 + gg) * 2 + 0];
  r2[t] = part[(t * 8 + gg) * 2 + 1];
  __syncthreads();
  for (int st = 128; st > 0; st >>= 1) {
    if (t < st) { r1[t] += r1[t + st]; r2[t] += r2[t + st]; }
    __syncthreads();
  }
  if (t == 0) {
    const float inv_n = 1.f / (16.f * HW);
    float mu = r1[0] * inv_n;
    float var = r2[0] * inv_n - mu * mu;
    stat[gg * 2 + 0] = mu;
    stat[gg * 2 + 1] = rsqrtf(var + 1e-5f);
  }
}

__global__ __launch_bounds__(256) void gn_apply(
    const float* __restrict__ y, const float* __restrict__ stat,
    const float* __restrict__ gn_w, const float* __restrict__ gn_b,
    float* __restrict__ outp) {
  const int i = (blockIdx.x * 256 + threadIdx.x) * 4;
  const int ch = i >> 14;
  const int g = ch >> 4;
  float mu = stat[g * 2], rs = stat[g * 2 + 1];
  float w = gn_w[ch] * rs;
  float b = gn_b[ch] - mu * w;
  float4 v = *(const float4*)&y[i];
  float4 r = {v.x * w + b, v.y * w + b, v.z * w + b, v.w * w + b};
  *(float4*)&outp[i] = r;
}

// ---------------------------------------------------------------------------
extern "C" void kernel_launch(void* const* d_in, const int* in_sizes, int n_in,
                              void* d_out, int out_size, void* d_ws, size_t ws_size,
                              hipStream_t stream) {
  const float* x     = (const float*)d_in[0];
  const float* w_qkv = (const float*)d_in[1];
  const float* se_w1 = (const float*)d_in[2];
  const float* se_b1 = (const float*)d_in[3];
  const float* se_w2 = (const float*)d_in[4];
  const float* se_b2 = (const float*)d_in[5];
  const float* out_w = (const float*)d_in[6];
  const float* out_b = (const float*)d_in[7];
  const float* gn_w  = (const float*)d_in[8];
  const float* gn_b  = (const float*)d_in[9];
  float* out = (float*)d_out;

  float* ws = (float*)d_ws;
  float* zpart = ws;                         // 131072 f
  float* se_s  = zpart + 131072;             // 128 f
  float* ybuf  = se_s + 128;                 // 2097152 f
  float* part  = ybuf + 2097152;             // 4096 f
  float* stat  = part + 4096;                // 16 f
  unsigned short* w_bf  = (unsigned short*)(stat + 16);  // 49152 sh
  unsigned short* x_t   = w_bf + 49152;                  // 2097152 sh
  unsigned short* q_t   = x_t + 2097152;                 // 2097152 sh
  unsigned short* k_t   = q_t + 2097152;                 // 2097152 sh
  unsigned short* v_bf  = k_t + 2097152;                 // 2097152 sh
  unsigned short* vz    = v_bf + 2097152;                // 2097152 sh
  unsigned short* w_g   = vz + 2097152;                  // 16384 sh
  unsigned short* att_t = w_g + 16384;                   // 2*2097152 sh

  cast_w<<<48, 256, 0, stream>>>(w_qkv, w_bf);
  cast_transpose_x<<<256, 256, 0, stream>>>(x, x_t);
  gemm_qkv<<<256, 512, 0, stream>>>(w_bf, x_t, q_t, k_t, v_bf);
  row_mean_v<<<128, 256, 0, stream>>>(v_bf, se_s);
  se_mlp<<<1, 128, 0, stream>>>(se_s, se_w1, se_b1, se_w2, se_b2, out_w, w_g);
  attn_stats_mfma<<<dim3(8, 32, 2), 512, 0, stream>>>(q_t, k_t, zpart);
  vz_cast<<<1024, 256, 0, stream>>>(v_bf, zpart, vz);
  attn_apply_mfma<<<dim3(8, 32, 2), 512, 0, stream>>>(q_t, k_t, vz, att_t);
  gemm_out<<<256, 256, 0, stream>>>(w_g, att_t, out_b, ybuf, part);
  gn_finalize<<<8, 256, 0, stream>>>(part, stat);
  gn_apply<<<2048, 256, 0, stream>>>(ybuf, stat, gn_w, gn_b, out);
}